// Round 5
// baseline (84.315 us; speedup 1.0000x reference)
//
#include <hip/hip_runtime.h>

// MultiScaleGraphConstruction: out[s,b,i,j] = dist(b,i,j) if MIN_DIST < dist < r_s else 0
//
// R5: coarsened blocks. One block = one scale plane x 8 consecutive rows
// (64 KB contiguous writes), grid (2048,1,3). Amortizes block prologue 8x,
// gives fill-kernel-like long linear write runs per CU. j-side pos loads
// hoisted out of the row loop (L1/reg reuse); 8 i-row coords hoisted.
//
// Mask equivalence (bit-exact vs reference f32 arithmetic):
//   ref: dist = sqrt_rn(max(sq,1e-12)); mask = (dist < r) & (dist > 1e-6)
//   sqrt_rn monotone + correctly rounded =>
//     dist < 3  <=>  sq < 9.0f
//     dist < 5  <=>  sq < nextbelow(25)  (sqrt_rn(nextbelow(25)) == 5 exactly)
//     dist < 8  <=>  sq < 64.0f
//   dist > 1e-6 <=> sq > 0. Value via v_sqrt_f32 (<=1 ulp << 0.16 threshold).
// sq computed in reference order, no FMA contraction.

namespace {
constexpr int B = 8;
constexpr int N = 2048;                       // pos is (B, N, 3) f32
constexpr long long NN  = (long long)N * N;   // 4,194,304
constexpr long long BNN = (long long)B * NN;  // 33,554,432
constexpr int RPB = 8;                        // rows per block (divides N)
typedef float vf4 __attribute__((ext_vector_type(4)));
}

__global__ __launch_bounds__(256) void msgc_kernel(const float* __restrict__ pos,
                                                   float* __restrict__ out) {
    const int s    = blockIdx.z;               // scale plane 0..2
    const int row0 = blockIdx.x * RPB;         // global row (b*N + i), 8-row group
    const int b    = row0 >> 11;
    const int i0   = row0 & (N - 1);           // 8-row groups never cross b (8 | 2048)

    // squared-distance cutoff, bit-exact equivalent of (sqrt_rn(sq) < r)
    const float thr = (s == 0) ? 9.0f
                    : (s == 1) ? __uint_as_float(0x41C7FFFFu)   // nextbelow(25.0f)
                               : 64.0f;

    const float* __restrict__ pb = pos + (size_t)b * N * 3;

    float xi[RPB], yi[RPB], zi[RPB];
#pragma unroll
    for (int r = 0; r < RPB; ++r) {
        xi[r] = pb[3 * (i0 + r) + 0];
        yi[r] = pb[3 * (i0 + r) + 1];
        zi[r] = pb[3 * (i0 + r) + 2];
    }

    // j-side positions for this thread's 8 j's (two groups of 4), loaded once.
    float jx[2][4], jy[2][4], jz[2][4];
#pragma unroll
    for (int it = 0; it < 2; ++it) {
        const int j0 = (((int)threadIdx.x + (it << 8)) << 2);
        const vf4* p4 = reinterpret_cast<const vf4*>(pb + (size_t)j0 * 3);
        const vf4 a = p4[0];
        const vf4 c = p4[1];
        const vf4 e = p4[2];
        jx[it][0] = a.x; jx[it][1] = a.w; jx[it][2] = c.z; jx[it][3] = e.y;
        jy[it][0] = a.y; jy[it][1] = c.x; jy[it][2] = c.w; jy[it][3] = e.z;
        jz[it][0] = a.z; jz[it][1] = c.y; jz[it][2] = e.x; jz[it][3] = e.w;
    }

    float* __restrict__ oblk = out + (size_t)s * BNN + (size_t)b * NN + (size_t)i0 * N;

#pragma unroll
    for (int r = 0; r < RPB; ++r) {
        float* __restrict__ orow = oblk + (size_t)r * N;
#pragma unroll
        for (int it = 0; it < 2; ++it) {
            const int j0 = (((int)threadIdx.x + (it << 8)) << 2);
            vf4 v;
#pragma unroll
            for (int k = 0; k < 4; ++k) {
                const float dx = xi[r] - jx[it][k];
                const float dy = yi[r] - jy[it][k];
                const float dz = zi[r] - jz[it][k];
                // No FMA contraction; reference summation order.
                const float s0 = __fmul_rn(dx, dx);
                const float s1 = __fmul_rn(dy, dy);
                const float s2 = __fmul_rn(dz, dz);
                const float sq = __fadd_rn(__fadd_rn(s0, s1), s2);
                const float dist = __builtin_amdgcn_sqrtf(sq);  // value-only
                v[k] = ((sq > 0.0f) && (sq < thr)) ? dist : 0.0f;
            }
            __builtin_nontemporal_store(v, reinterpret_cast<vf4*>(orow + j0));
        }
    }
}

extern "C" void kernel_launch(void* const* d_in, const int* in_sizes, int n_in,
                              void* d_out, int out_size, void* d_ws, size_t ws_size,
                              hipStream_t stream) {
    const float* pos = (const float*)d_in[0];
    float* out = (float*)d_out;
    msgc_kernel<<<dim3((B * N) / RPB, 1, 3), dim3(256), 0, stream>>>(pos, out);
}

// Round 6
// 80.184 us; speedup vs baseline: 1.0515x; 1.0515x over previous
//
#include <hip/hip_runtime.h>

// MultiScaleGraphConstruction: out[s,b,i,j] = dist(b,i,j) if MIN_DIST < dist < r_s else 0
//
// R6: persistent grid-stride over output rows, mimicking the 6.9 TB/s fill
// kernel's access structure. rowId = flat index over (s,b,i); block n handles
// rows n, n+1024, ... so the co-resident write window is 1024 consecutive
// rows (8 MB) marching linearly -> maximal DRAM page/channel locality of the
// CONCURRENT write set (R5 showed a 128 MB in-flight span costs 20%).
// 1024 blocks @ 4 blocks/CU (launch_bounds(256,4)) = fully co-resident,
// zero launch churn, no grid-stride serialization tail.
//
// Mask equivalence (bit-exact vs reference f32 arithmetic):
//   ref: dist = sqrt_rn(max(sq,1e-12)); mask = (dist < r) & (dist > 1e-6)
//   sqrt_rn monotone + correctly rounded =>
//     dist < 3  <=>  sq < 9.0f
//     dist < 5  <=>  sq < nextbelow(25)  (sqrt_rn(nextbelow(25)) == 5 exactly)
//     dist < 8  <=>  sq < 64.0f
//   dist > 1e-6 <=> sq > 0. Value via v_sqrt_f32 (<=1 ulp << 0.16 threshold).
// sq computed in reference order, no FMA contraction.

namespace {
constexpr int B = 8;
constexpr int N = 2048;                 // pos is (B, N, 3) f32
constexpr int NROWS = 3 * B * N;        // 49152 output rows of length N (flat s,b,i)
constexpr int GRID = 1024;              // 4 blocks/CU, fully resident
constexpr int ITER = NROWS / GRID;      // 48 rows per block
typedef float vf4 __attribute__((ext_vector_type(4)));
}

__global__ __launch_bounds__(256, 4) void msgc_kernel(const float* __restrict__ pos,
                                                      float* __restrict__ out) {
    const int tid = (int)threadIdx.x;
    const float S5 = __uint_as_float(0x41C7FFFFu);  // nextbelow(25.0f)

    for (int t = 0; t < ITER; ++t) {
        const int row = (int)blockIdx.x + (t << 10);   // block-uniform rowId
        const int s   = row >> 14;                     // / (B*N)
        const int b   = (row >> 11) & (B - 1);
        const int i   = row & (N - 1);
        const float thr = (s == 0) ? 9.0f : (s == 1) ? S5 : 64.0f;

        const float* __restrict__ pb = pos + (size_t)b * (N * 3);
        const float xi = pb[3 * i + 0];   // block-uniform -> scalar loads
        const float yi = pb[3 * i + 1];
        const float zi = pb[3 * i + 2];

        float* __restrict__ orow = out + (size_t)row * N;

#pragma unroll
        for (int it = 0; it < 2; ++it) {
            const int j0 = ((tid + (it << 8)) << 2);   // 4 consecutive j
            const vf4* p4 = reinterpret_cast<const vf4*>(pb + (size_t)j0 * 3);
            const vf4 a = p4[0];
            const vf4 c = p4[1];
            const vf4 e = p4[2];
            const float jx[4] = {a.x, a.w, c.z, e.y};
            const float jy[4] = {a.y, c.x, c.w, e.z};
            const float jz[4] = {a.z, c.y, e.x, e.w};

            vf4 v;
#pragma unroll
            for (int k = 0; k < 4; ++k) {
                const float dx = xi - jx[k];
                const float dy = yi - jy[k];
                const float dz = zi - jz[k];
                // No FMA contraction; reference summation order.
                const float s0 = __fmul_rn(dx, dx);
                const float s1 = __fmul_rn(dy, dy);
                const float s2 = __fmul_rn(dz, dz);
                const float sq = __fadd_rn(__fadd_rn(s0, s1), s2);
                const float dist = __builtin_amdgcn_sqrtf(sq);  // value-only
                v[k] = ((sq > 0.0f) && (sq < thr)) ? dist : 0.0f;
            }
            __builtin_nontemporal_store(v, reinterpret_cast<vf4*>(orow + j0));
        }
    }
}

extern "C" void kernel_launch(void* const* d_in, const int* in_sizes, int n_in,
                              void* d_out, int out_size, void* d_ws, size_t ws_size,
                              hipStream_t stream) {
    const float* pos = (const float*)d_in[0];
    float* out = (float*)d_out;
    msgc_kernel<<<dim3(GRID), dim3(256), 0, stream>>>(pos, out);
}

// Round 7
// 64.543 us; speedup vs baseline: 1.3063x; 1.2423x over previous
//
#include <hip/hip_runtime.h>

// MultiScaleGraphConstruction: out[s,b,i,j] = dist(b,i,j) if MIN_DIST < dist < r_s else 0
//
// R7: exact R4 structure (best so far, 70.6us), single A/B toggle: PLAIN
// stores instead of nontemporal. Theory: the 7.0 TB/s fill kernel uses plain
// stores -> L2 allocates the lines and acts as a write-combining burst buffer
// (long linear DRAM bursts on writeback). nt defeats that aggregation.
// One block per (scale, b, i): each block writes one contiguous 8KB row of
// one plane. Dispatch order (x fastest, z slowest) keeps the concurrent
// write set to ~one plane's consecutive rows.
//
// Mask equivalence (bit-exact vs reference f32 arithmetic):
//   ref: dist = sqrt_rn(max(sq,1e-12)); mask = (dist < r) & (dist > 1e-6)
//   sqrt_rn monotone + correctly rounded =>
//     dist < 3  <=>  sq < 9.0f
//     dist < 5  <=>  sq < nextbelow(25)  (sqrt_rn(nextbelow(25)) == 5 exactly)
//     dist < 8  <=>  sq < 64.0f
//   dist > 1e-6 <=> sq > 0. Value via v_sqrt_f32 (<=1 ulp << 0.16 threshold).
// sq computed in reference order, no FMA contraction.

namespace {
constexpr int B = 8;
constexpr int N = 2048;                       // pos is (B, N, 3) f32
constexpr long long NN  = (long long)N * N;   // 4,194,304
constexpr long long BNN = (long long)B * NN;  // 33,554,432
typedef float vf4 __attribute__((ext_vector_type(4)));
}

__global__ __launch_bounds__(256) void msgc_kernel(const float* __restrict__ pos,
                                                   float* __restrict__ out) {
    const int bi = blockIdx.x;            // one block per output row (b,i)
    const int b  = bi >> 11;
    const int i  = bi & (N - 1);
    const int s  = blockIdx.z;            // scale plane 0..2

    // squared-distance cutoff, bit-exact equivalent of (sqrt_rn(sq) < r)
    const float thr = (s == 0) ? 9.0f
                    : (s == 1) ? __uint_as_float(0x41C7FFFFu)   // nextbelow(25.0f)
                               : 64.0f;

    const float* __restrict__ pb = pos + (size_t)b * N * 3;
    const float xi = pb[3 * i + 0];
    const float yi = pb[3 * i + 1];
    const float zi = pb[3 * i + 2];

    float* __restrict__ orow = out + (size_t)s * BNN + (size_t)b * NN + (size_t)i * N;

#pragma unroll
    for (int it = 0; it < 2; ++it) {
        const int j0 = (((int)threadIdx.x + (it << 8)) << 2);  // 4 consecutive j
        const vf4* p4 = reinterpret_cast<const vf4*>(pb + (size_t)j0 * 3);
        const vf4 a = p4[0];
        const vf4 c = p4[1];
        const vf4 e = p4[2];

        const float jx[4] = {a.x, a.w, c.z, e.y};
        const float jy[4] = {a.y, c.x, c.w, e.z};
        const float jz[4] = {a.z, c.y, e.x, e.w};

        vf4 r;
#pragma unroll
        for (int k = 0; k < 4; ++k) {
            const float dx = xi - jx[k];
            const float dy = yi - jy[k];
            const float dz = zi - jz[k];
            // No FMA contraction; reference summation order.
            const float s0 = __fmul_rn(dx, dx);
            const float s1 = __fmul_rn(dy, dy);
            const float s2 = __fmul_rn(dz, dz);
            const float sq = __fadd_rn(__fadd_rn(s0, s1), s2);
            const float dist = __builtin_amdgcn_sqrtf(sq);  // value-only
            r[k] = ((sq > 0.0f) && (sq < thr)) ? dist : 0.0f;
        }

        *reinterpret_cast<vf4*>(orow + j0) = r;   // PLAIN store (the A/B toggle)
    }
}

extern "C" void kernel_launch(void* const* d_in, const int* in_sizes, int n_in,
                              void* d_out, int out_size, void* d_ws, size_t ws_size,
                              hipStream_t stream) {
    const float* pos = (const float*)d_in[0];
    float* out = (float*)d_out;
    msgc_kernel<<<dim3(B * N, 1, 3), dim3(256), 0, stream>>>(pos, out);
}